// Round 3
// baseline (219.265 us; speedup 1.0000x reference)
//
#include <hip/hip_runtime.h>
#include <hip/hip_bf16.h>

typedef _Float16 f16x4 __attribute__((ext_vector_type(4)));
typedef _Float16 f16x8 __attribute__((ext_vector_type(8)));
typedef float f32x4 __attribute__((ext_vector_type(4)));

#define IN_CH   64
#define OUT_CH  64
#define W_TOT   2048
#define KW      3
#define B_TOT   32
#define CK      192     // IN_CH * KW
#define LDSTRIDE 200    // CK + 8 halfs pad -> conflict-free b128 frag reads

__global__ __launch_bounds__(256, 4)
void lc1d_kernel(const float* __restrict__ x,
                 const float* __restrict__ wts,
                 const float* __restrict__ bias,
                 float* __restrict__ out) {
    __shared__ _Float16 Wt[OUT_CH * LDSTRIDE];   // 64 x 200 f16 = 25.6 KB
    __shared__ _Float16 Xp[B_TOT * LDSTRIDE];    // 32 x 200 f16 = 12.8 KB

    const int tid = threadIdx.x;
    const int bid = blockIdx.x;
    // XCD-bijective swizzle: each XCD gets a contiguous 256-w chunk.
    // weights stream per XCD = contiguous 12.6 MB; out/x lines stay in one L2.
    const int w = (bid & 7) * 256 + (bid >> 3);

    // ---- stage weights[w]: 12288 contiguous f32, coalesced float4, cvt->f16 LDS [o][ck]
    const float* wsrc = wts + (size_t)w * (OUT_CH * CK);
    #pragma unroll
    for (int i = 0; i < 12; ++i) {
        int e = i * 1024 + tid * 4;          // 4 consecutive elems; 192%4==0 -> never crosses a row
        float4 v = *reinterpret_cast<const float4*>(wsrc + e);
        int r = e / CK;
        int c = e - r * CK;
        f16x4 h = { (_Float16)v.x, (_Float16)v.y, (_Float16)v.z, (_Float16)v.w };
        *reinterpret_cast<f16x4*>(&Wt[r * LDSTRIDE + c]) = h;
    }

    // ---- stage x patch: Xp[b][c*3+k] = x[b][c][w-1+k] (0 outside) ----
    #pragma unroll
    for (int j = 0; j < 8; ++j) {
        int p = tid + 256 * j;               // (b,c) pair, p == b*64 + c
        int b = p >> 6;
        int c = p & 63;
        const float* row = x + (size_t)p * W_TOT;
        #pragma unroll
        for (int k = 0; k < KW; ++k) {
            int v = w - 1 + k;
            float xv = (v >= 0 && v < W_TOT) ? row[v] : 0.0f;
            Xp[b * LDSTRIDE + c * 3 + k] = (_Float16)xv;
        }
    }

    __syncthreads();

    // ---- 32x64x192 GEMM via mfma_f32_16x16x32_f16 ----
    // wave wv owns o-tile [16wv,16wv+16); both b-tiles; K = 6 steps of 32.
    const int lane = tid & 63;
    const int wv   = tid >> 6;       // 0..3
    const int l15  = lane & 15;
    const int kg   = lane >> 4;      // 0..3 k-group

    const _Float16* Xb = &Xp[l15 * LDSTRIDE + kg * 8];
    const _Float16* Wb = &Wt[(wv * 16 + l15) * LDSTRIDE + kg * 8];

    f32x4 acc0 = {0.f, 0.f, 0.f, 0.f};
    f32x4 acc1 = {0.f, 0.f, 0.f, 0.f};
    #pragma unroll
    for (int kk = 0; kk < 6; ++kk) {
        f16x8 a0 = *reinterpret_cast<const f16x8*>(Xb + kk * 32);
        f16x8 a1 = *reinterpret_cast<const f16x8*>(Xb + 16 * LDSTRIDE + kk * 32);
        f16x8 bf = *reinterpret_cast<const f16x8*>(Wb + kk * 32);
        // D[r][c] = sum_k A[r][k]*B[c][k]; A rows = b (reg axis), B rows = o (lane&15)
        acc0 = __builtin_amdgcn_mfma_f32_16x16x32_f16(a0, bf, acc0, 0, 0, 0);
        acc1 = __builtin_amdgcn_mfma_f32_16x16x32_f16(a1, bf, acc1, 0, 0, 0);
    }

    // ---- epilogue: D row = (lane>>4)*4 + reg = b-within-tile; col = lane&15 = o-within-tile
    const int o = wv * 16 + l15;
    const float bv = bias[o * W_TOT + w];
    #pragma unroll
    for (int r = 0; r < 4; ++r) {
        int b0 = kg * 4 + r;
        out[((size_t)(b0 * OUT_CH + o)) * W_TOT + w] = acc0[r] + bv;
        int b1 = 16 + kg * 4 + r;
        out[((size_t)(b1 * OUT_CH + o)) * W_TOT + w] = acc1[r] + bv;
    }
}

extern "C" void kernel_launch(void* const* d_in, const int* in_sizes, int n_in,
                              void* d_out, int out_size, void* d_ws, size_t ws_size,
                              hipStream_t stream) {
    const float* x    = (const float*)d_in[0];
    const float* wts  = (const float*)d_in[1];
    const float* bias = (const float*)d_in[2];
    float* out = (float*)d_out;
    hipLaunchKernelGGL(lc1d_kernel, dim3(2048), dim3(256), 0, stream,
                       x, wts, bias, out);
}

// Round 4
// 207.664 us; speedup vs baseline: 1.0559x; 1.0559x over previous
//
#include <hip/hip_runtime.h>

typedef _Float16 f16x8 __attribute__((ext_vector_type(8)));
typedef float f32x4 __attribute__((ext_vector_type(4)));

#define IN_CH   64
#define OUT_CH  64
#define W_TOT   2048
#define KW      3
#define B_TOT   32
#define CK      192     // IN_CH * KW
#define LDST    200     // halfs; 400 B row stride = 25*16 -> conflict-free b128 frag reads

static __device__ __forceinline__ f16x8 cvt8(const float4& a, const float4& b) {
    f16x8 r;
    r[0] = (_Float16)a.x; r[1] = (_Float16)a.y; r[2] = (_Float16)a.z; r[3] = (_Float16)a.w;
    r[4] = (_Float16)b.x; r[5] = (_Float16)b.y; r[6] = (_Float16)b.z; r[7] = (_Float16)b.w;
    return r;
}

__global__ __launch_bounds__(256, 5)
void lc1d_kernel(const float* __restrict__ x,
                 const float* __restrict__ wts,
                 const float* __restrict__ bias,
                 float* __restrict__ out) {
    __shared__ _Float16 Xp[B_TOT * LDST];    // 12.8 KB only -> ~5 blocks/CU

    const int tid = threadIdx.x;
    const int bid = blockIdx.x;
    // XCD-bijective swizzle (2048 % 8 == 0): contiguous 256-w chunk per XCD.
    const int w = (bid & 7) * 256 + (bid >> 3);

    const int lane = tid & 63;
    const int wv   = tid >> 6;       // 0..3 -> o-tile
    const int l15  = lane & 15;
    const int kg   = lane >> 4;      // 0..3 k-group

    // ---- x window loads FIRST (so LDS-write vmcnt doesn't drain the weight stream)
    // Per row (b,c): need x[p][w-1..w+1]; two aligned float2 cover it. Block-uniform branches.
    float xv[8][3];
    #pragma unroll
    for (int j = 0; j < 8; ++j) {
        const float* row = x + (size_t)(tid + 256 * j) * W_TOT;
        if (w == 0) {
            float2 lo = *reinterpret_cast<const float2*>(row);
            xv[j][0] = 0.f;  xv[j][1] = lo.x; xv[j][2] = lo.y;
        } else if (w == W_TOT - 1) {
            float2 lo = *reinterpret_cast<const float2*>(row + W_TOT - 2);
            xv[j][0] = lo.x; xv[j][1] = lo.y; xv[j][2] = 0.f;
        } else if ((w - 1) & 1) {
            float2 lo = *reinterpret_cast<const float2*>(row + (w - 1 - 1));
            float2 hi = *reinterpret_cast<const float2*>(row + (w - 1 + 1));
            xv[j][0] = lo.y; xv[j][1] = hi.x; xv[j][2] = hi.y;
        } else {
            float2 lo = *reinterpret_cast<const float2*>(row + (w - 1));
            float2 hi = *reinterpret_cast<const float2*>(row + (w + 1));
            xv[j][0] = lo.x; xv[j][1] = lo.y; xv[j][2] = hi.x;
        }
    }

    // ---- weight B-frags: DIRECT global -> reg (no LDS; weights have zero reuse).
    // lane (o = wv*16+l15, kg): floats at o*192 + ks*32 + kg*8 + {0..7}; all 16B-aligned.
    const int o = wv * 16 + l15;
    const float* wsrc = wts + (size_t)w * (OUT_CH * CK) + o * CK + kg * 8;
    float4 wf[6][2];
    #pragma unroll
    for (int ks = 0; ks < 6; ++ks) {
        wf[ks][0] = *reinterpret_cast<const float4*>(wsrc + ks * 32);
        wf[ks][1] = *reinterpret_cast<const float4*>(wsrc + ks * 32 + 4);
    }

    const float bv = bias[o * W_TOT + w];

    // ---- stage x patch to LDS: Xp[b][c*3+k]
    #pragma unroll
    for (int j = 0; j < 8; ++j) {
        int p = tid + 256 * j;
        int b = p >> 6;
        int c = p & 63;
        _Float16* dst = &Xp[b * LDST + c * 3];
        dst[0] = (_Float16)xv[j][0];
        dst[1] = (_Float16)xv[j][1];
        dst[2] = (_Float16)xv[j][2];
    }

    // ---- convert weight frags f32 -> f16 (frees the f32 regs before the barrier)
    f16x8 bw[6];
    #pragma unroll
    for (int ks = 0; ks < 6; ++ks) bw[ks] = cvt8(wf[ks][0], wf[ks][1]);

    __syncthreads();

    // ---- 32x64x192 GEMM: wave = o-tile, both b-tiles, 6 K-steps of 32
    const _Float16* Xb = &Xp[l15 * LDST + kg * 8];
    f32x4 acc0 = {0.f, 0.f, 0.f, 0.f};
    f32x4 acc1 = {0.f, 0.f, 0.f, 0.f};
    #pragma unroll
    for (int ks = 0; ks < 6; ++ks) {
        f16x8 a0 = *reinterpret_cast<const f16x8*>(Xb + ks * 32);
        f16x8 a1 = *reinterpret_cast<const f16x8*>(Xb + 16 * LDST + ks * 32);
        acc0 = __builtin_amdgcn_mfma_f32_16x16x32_f16(a0, bw[ks], acc0, 0, 0, 0);
        acc1 = __builtin_amdgcn_mfma_f32_16x16x32_f16(a1, bw[ks], acc1, 0, 0, 0);
    }

    // ---- epilogue: D row = kg*4+reg = b-in-tile; col = l15 = o-in-tile (verified R3)
    #pragma unroll
    for (int r = 0; r < 4; ++r) {
        int b0 = kg * 4 + r;
        out[((size_t)(b0 * OUT_CH + o)) * W_TOT + w] = acc0[r] + bv;
        int b1 = 16 + kg * 4 + r;
        out[((size_t)(b1 * OUT_CH + o)) * W_TOT + w] = acc1[r] + bv;
    }
}

extern "C" void kernel_launch(void* const* d_in, const int* in_sizes, int n_in,
                              void* d_out, int out_size, void* d_ws, size_t ws_size,
                              hipStream_t stream) {
    const float* x    = (const float*)d_in[0];
    const float* wts  = (const float*)d_in[1];
    const float* bias = (const float*)d_in[2];
    float* out = (float*)d_out;
    hipLaunchKernelGGL(lc1d_kernel, dim3(2048), dim3(256), 0, stream,
                       x, wts, bias, out);
}

// Round 7
// 196.225 us; speedup vs baseline: 1.1174x; 1.0583x over previous
//
#include <hip/hip_runtime.h>
#include <stdint.h>

typedef _Float16 f16x8 __attribute__((ext_vector_type(8)));
typedef float f32x4 __attribute__((ext_vector_type(4)));

#define IN_CH   64
#define OUT_CH  64
#define W_TOT   2048
#define KW      3
#define B_TOT   32
#define CK      192     // IN_CH * KW
#define XPST    200     // Xp stride in halfs; 400 B = 25*16 -> conflict-free A-frag reads

static __device__ __forceinline__ f16x8 cvt8(f32x4 a, f32x4 b) {
    f16x8 r;
    r[0] = (_Float16)a[0]; r[1] = (_Float16)a[1]; r[2] = (_Float16)a[2]; r[3] = (_Float16)a[3];
    r[4] = (_Float16)b[0]; r[5] = (_Float16)b[1]; r[6] = (_Float16)b[2]; r[7] = (_Float16)b[3];
    return r;
}

__global__ __launch_bounds__(256, 2)
void lc1d_kernel(const float* __restrict__ x,
                 const float* __restrict__ wts,
                 const float* __restrict__ bias,
                 float* __restrict__ out) {
    __shared__ float    Wb[OUT_CH * CK];     // 48 KB f32, XOR-swizzled storage
    __shared__ _Float16 Xp[B_TOT * XPST];    // 12.8 KB

    const int tid  = threadIdx.x;
    const int bid  = blockIdx.x;
    // XCD-bijective swizzle (2048 % 8 == 0): contiguous 256-w chunk per XCD.
    const int w    = (bid & 7) * 256 + (bid >> 3);
    const int lane = tid & 63;
    const int wv   = tid >> 6;       // 0..3: wave owns o-tile [wv*16, wv*16+16)
    const int l15  = lane & 15;
    const int kg   = lane >> 4;      // 0..3 k-group

    // ---- weight panel DMA: async global -> LDS, zero VGPR cost, 12 in flight.
    // Wave wv stages its own 12 KB o-range; LDS linear, source pre-swizzled so
    // that LDS[d] = W[d ^ ((row(d)&7)<<4)]  (involution, row-preserving).
    {
        const char* wbase = (const char*)(wts + (size_t)w * (OUT_CH * CK));
        #pragma unroll
        for (int i = 0; i < 12; ++i) {
            int d   = wv * 12288 + i * 1024 + lane * 16;   // linear dest byte
            int o   = d / 768;                             // 768 B per o-row
            int src = d ^ ((o & 7) << 4);
            __builtin_amdgcn_global_load_lds(
                (const __attribute__((address_space(1))) uint32_t*)(wbase + src),
                (__attribute__((address_space(3))) uint32_t*)((char*)Wb + wv * 12288 + i * 1024),
                16, 0, 0);
        }
    }

    // ---- x window loads: 16 independent float2, issued while the DMA flies.
    float xv[8][3];
    #pragma unroll
    for (int j = 0; j < 8; ++j) {
        const float* row = x + (size_t)(tid + 256 * j) * W_TOT;
        if (w == 0) {
            float2 lo = *reinterpret_cast<const float2*>(row);
            xv[j][0] = 0.f;  xv[j][1] = lo.x; xv[j][2] = lo.y;
        } else if (w == W_TOT - 1) {
            float2 lo = *reinterpret_cast<const float2*>(row + W_TOT - 2);
            xv[j][0] = lo.x; xv[j][1] = lo.y; xv[j][2] = 0.f;
        } else if ((w - 1) & 1) {
            float2 lo = *reinterpret_cast<const float2*>(row + (w - 2));
            float2 hi = *reinterpret_cast<const float2*>(row + w);
            xv[j][0] = lo.y; xv[j][1] = hi.x; xv[j][2] = hi.y;
        } else {
            float2 lo = *reinterpret_cast<const float2*>(row + (w - 1));
            float2 hi = *reinterpret_cast<const float2*>(row + (w + 1));
            xv[j][0] = lo.x; xv[j][1] = lo.y; xv[j][2] = hi.x;
        }
    }

    const int o = wv * 16 + l15;
    const float bv = bias[o * W_TOT + w];

    // ---- stage x patch to LDS: Xp[b][c*3+k]
    #pragma unroll
    for (int j = 0; j < 8; ++j) {
        int p = tid + 256 * j;
        _Float16* dst = &Xp[(p >> 6) * XPST + (p & 63) * 3];
        dst[0] = (_Float16)xv[j][0];
        dst[1] = (_Float16)xv[j][1];
        dst[2] = (_Float16)xv[j][2];
    }

    __syncthreads();   // drains vmcnt(0) (all DMAs) + lgkmcnt (Xp writes)

    // ---- 32x64x192 GEMM: wave = o-tile, both b-tiles, 6 K-steps of 32
    const _Float16* Xb   = &Xp[l15 * XPST + kg * 8];
    const char*     wrow = (const char*)Wb + o * 768;   // o*768 has bits 4-6 clear
    const int       sm   = (o & 7) << 4;

    f32x4 acc0 = {0.f, 0.f, 0.f, 0.f};
    f32x4 acc1 = {0.f, 0.f, 0.f, 0.f};
    #pragma unroll
    for (int ks = 0; ks < 6; ++ks) {
        int Cb = ks * 128 + kg * 32;
        f32x4 b0 = *reinterpret_cast<const f32x4*>(wrow + (Cb ^ sm));
        f32x4 b1 = *reinterpret_cast<const f32x4*>(wrow + ((Cb + 16) ^ sm));
        f16x8 bw = cvt8(b0, b1);
        f16x8 a0 = *reinterpret_cast<const f16x8*>(Xb + ks * 32);
        f16x8 a1 = *reinterpret_cast<const f16x8*>(Xb + 16 * XPST + ks * 32);
        acc0 = __builtin_amdgcn_mfma_f32_16x16x32_f16(a0, bw, acc0, 0, 0, 0);
        acc1 = __builtin_amdgcn_mfma_f32_16x16x32_f16(a1, bw, acc1, 0, 0, 0);
    }

    // ---- epilogue: D row = kg*4+reg = b-in-tile; col = l15 = o-in-tile (verified R3/R4)
    #pragma unroll
    for (int r = 0; r < 4; ++r) {
        int b0 = kg * 4 + r;
        out[((size_t)(b0 * OUT_CH + o)) * W_TOT + w] = acc0[r] + bv;
        int b1 = 16 + kg * 4 + r;
        out[((size_t)(b1 * OUT_CH + o)) * W_TOT + w] = acc1[r] + bv;
    }
}

extern "C" void kernel_launch(void* const* d_in, const int* in_sizes, int n_in,
                              void* d_out, int out_size, void* d_ws, size_t ws_size,
                              hipStream_t stream) {
    const float* x    = (const float*)d_in[0];
    const float* wts  = (const float*)d_in[1];
    const float* bias = (const float*)d_in[2];
    float* out = (float*)d_out;
    hipLaunchKernelGGL(lc1d_kernel, dim3(2048), dim3(256), 0, stream,
                       x, wts, bias, out);
}

// Round 14
// 184.340 us; speedup vs baseline: 1.1895x; 1.0645x over previous
//
#include <hip/hip_runtime.h>
#include <stdint.h>

typedef _Float16 f16x8 __attribute__((ext_vector_type(8)));
typedef _Float16 f16x4v __attribute__((ext_vector_type(4)));
typedef float f32x4 __attribute__((ext_vector_type(4)));

#define W_TOT  2048
#define CK     192      // IN_CH * KW
#define NW     4        // w positions per block
#define WROWST 200      // Wb row stride in halfs (400 B = 3*128+16 -> frag reads 2-way max)
#define XPST   200      // Xp row stride in halfs

__global__ __launch_bounds__(256, 2)
void lc1d_kernel(const float* __restrict__ x,
                 const float* __restrict__ wts,
                 const float* __restrict__ bias,
                 float* __restrict__ out) {
    __shared__ _Float16 Wb[2][64 * WROWST];  // 2 x 25.6 KB f16, double-buffered weight panel
    __shared__ _Float16 Xp[32 * XPST];       // 12.8 KB; rebuilt per iter from regs
    // total 64 KB -> 2 blocks/CU

    const int tid  = threadIdx.x;
    const int bid  = blockIdx.x;
    // 512 blocks; XCD k owns contiguous w range [k*256,(k+1)*256): weight stream
    // per XCD is one contiguous 12.6 MB, out/x lines stay in one L2.
    const int w0   = ((bid & 7) * 64 + (bid >> 3)) * NW;

    const int lane = tid & 63;
    const int wv   = tid >> 6;       // wave -> o-tile
    const int l15  = lane & 15;
    const int kg   = lane >> 4;
    const int o    = wv * 16 + l15;

    // ---- prologue: x window [w0-1, w0+NW] = 6 f32 per row, 8 rows/thread, loaded ONCE
    float xw[8][6];
    #pragma unroll
    for (int j = 0; j < 8; ++j) {
        const float* row = x + (size_t)(tid + 256 * j) * W_TOT;
        if (w0 == 0) {
            float2 a = *(const float2*)(row + 0);
            float2 b = *(const float2*)(row + 2);
            float2 c = *(const float2*)(row + 4);
            xw[j][0] = 0.f;  xw[j][1] = a.x; xw[j][2] = a.y;
            xw[j][3] = b.x;  xw[j][4] = b.y; xw[j][5] = c.x;
        } else if (w0 == W_TOT - NW) {
            float2 a = *(const float2*)(row + W_TOT - 6);
            float2 b = *(const float2*)(row + W_TOT - 4);
            float2 c = *(const float2*)(row + W_TOT - 2);
            xw[j][0] = a.y; xw[j][1] = b.x; xw[j][2] = b.y;
            xw[j][3] = c.x; xw[j][4] = c.y; xw[j][5] = 0.f;
        } else {
            float2 a = *(const float2*)(row + w0 - 2);
            float2 b = *(const float2*)(row + w0);
            float2 c = *(const float2*)(row + w0 + 2);
            float2 d = *(const float2*)(row + w0 + 4);
            xw[j][0] = a.y; xw[j][1] = b.x; xw[j][2] = b.y;
            xw[j][3] = c.x; xw[j][4] = c.y; xw[j][5] = d.x;
        }
    }

    // weight panel 0 loads (12 x float4/thread, wave covers 4 KB contiguous per instr)
    f32x4 wr[12];
    {
        const float* wp = wts + (size_t)w0 * (64 * CK);
        #pragma unroll
        for (int t = 0; t < 12; ++t)
            wr[t] = *(const f32x4*)(wp + t * 1024 + tid * 4);
    }
    const f32x4 bv = *(const f32x4*)(bias + (size_t)o * W_TOT + w0);  // w0 % 4 == 0

    // x -> f16 once (slot s = x[.][w0-1+s])
    _Float16 xh[8][6];
    #pragma unroll
    for (int j = 0; j < 8; ++j)
        #pragma unroll
        for (int s = 0; s < 6; ++s) xh[j][s] = (_Float16)xw[j][s];

    // store panel 0: e -> row e/192, col e%192
    #pragma unroll
    for (int t = 0; t < 12; ++t) {
        int e = t * 1024 + tid * 4;
        int r = e / 192, c = e % 192;
        f16x4v h = { (_Float16)wr[t][0], (_Float16)wr[t][1],
                     (_Float16)wr[t][2], (_Float16)wr[t][3] };
        *(f16x4v*)(&Wb[0][r * WROWST + c]) = h;
    }
    // Xp for iter 0
    #pragma unroll
    for (int j = 0; j < 8; ++j) {
        int p = tid + 256 * j;
        _Float16* dst = &Xp[(p >> 6) * XPST + (p & 63) * 3];
        dst[0] = xh[j][0]; dst[1] = xh[j][1]; dst[2] = xh[j][2];
    }
    __syncthreads();

    f32x4 acc[NW][2];
    #pragma unroll
    for (int i = 0; i < NW; ++i) { acc[i][0] = {0.f,0.f,0.f,0.f}; acc[i][1] = {0.f,0.f,0.f,0.f}; }

    const _Float16* Xb = &Xp[l15 * XPST + kg * 8];

    #pragma unroll
    for (int i = 0; i < NW; ++i) {
        // issue next-panel loads FIRST: latency hides under this iter's MFMA phase
        if (i < NW - 1) {
            const float* wp = wts + (size_t)(w0 + i + 1) * (64 * CK);
            #pragma unroll
            for (int t = 0; t < 12; ++t)
                wr[t] = *(const f32x4*)(wp + t * 1024 + tid * 4);
        }
        const _Float16* Wcur = &Wb[i & 1][o * WROWST + kg * 8];
        #pragma unroll
        for (int ks = 0; ks < 6; ++ks) {
            f16x8 a0 = *(const f16x8*)(Xb + ks * 32);
            f16x8 a1 = *(const f16x8*)(Xb + 16 * XPST + ks * 32);
            f16x8 bw = *(const f16x8*)(Wcur + ks * 32);
            acc[i][0] = __builtin_amdgcn_mfma_f32_16x16x32_f16(a0, bw, acc[i][0], 0, 0, 0);
            acc[i][1] = __builtin_amdgcn_mfma_f32_16x16x32_f16(a1, bw, acc[i][1], 0, 0, 0);
        }
        __syncthreads();   // all waves done reading Xp & Wb[i&1]
        if (i < NW - 1) {
            // write next weight panel (vmcnt drained here, after a full compute phase)
            _Float16* Wnxt = &Wb[(i + 1) & 1][0];
            #pragma unroll
            for (int t = 0; t < 12; ++t) {
                int e = t * 1024 + tid * 4;
                int r = e / 192, c = e % 192;
                f16x4v h = { (_Float16)wr[t][0], (_Float16)wr[t][1],
                             (_Float16)wr[t][2], (_Float16)wr[t][3] };
                *(f16x4v*)(&Wnxt[r * WROWST + c]) = h;
            }
            // rebuild Xp for iter i+1 from registers (no global traffic)
            #pragma unroll
            for (int j = 0; j < 8; ++j) {
                int p = tid + 256 * j;
                _Float16* dst = &Xp[(p >> 6) * XPST + (p & 63) * 3];
                dst[0] = xh[j][i + 1]; dst[1] = xh[j][i + 2]; dst[2] = xh[j][i + 3];
            }
            __syncthreads();
        }
    }

    // ---- epilogue: b = bt*16 + kg*4 + r; one float4 (w0..w0+3) per (b,o) row
    #pragma unroll
    for (int bt = 0; bt < 2; ++bt)
        #pragma unroll
        for (int r = 0; r < 4; ++r) {
            int b = bt * 16 + kg * 4 + r;
            f32x4 v = { acc[0][bt][r] + bv[0], acc[1][bt][r] + bv[1],
                        acc[2][bt][r] + bv[2], acc[3][bt][r] + bv[3] };
            *(f32x4*)(out + ((size_t)(b * 64 + o)) * W_TOT + w0) = v;
        }
}

extern "C" void kernel_launch(void* const* d_in, const int* in_sizes, int n_in,
                              void* d_out, int out_size, void* d_ws, size_t ws_size,
                              hipStream_t stream) {
    const float* x    = (const float*)d_in[0];
    const float* wts  = (const float*)d_in[1];
    const float* bias = (const float*)d_in[2];
    float* out = (float*)d_out;
    hipLaunchKernelGGL(lc1d_kernel, dim3(512), dim3(256), 0, stream,
                       x, wts, bias, out);
}